// Round 5
// baseline (378.278 us; speedup 1.0000x reference)
//
#include <hip/hip_runtime.h>

#define Snum 2048
#define SCALE 0.08838834764831845f

typedef __attribute__((ext_vector_type(8))) __bf16 bf16x8;
typedef __attribute__((ext_vector_type(4))) float f32x4;

__device__ inline unsigned short f2bf(float f) {
    unsigned int u = __float_as_uint(f);
    unsigned int r = u + 0x7FFFu + ((u >> 16) & 1u);
    return (unsigned short)(r >> 16);
}
__device__ inline float bf2f(unsigned short u) {
    return __uint_as_float(((unsigned)u) << 16);
}
__device__ inline void gld_lds16(const unsigned short* g, unsigned short* l) {
    __builtin_amdgcn_global_load_lds(
        (const __attribute__((address_space(1))) unsigned int*)g,
        (__attribute__((address_space(3))) unsigned int*)l, 16, 0, 0);
}

// ---------------- all weight transposes fused: [K][N] fp32 -> [N][K] bf16 ----------------
__global__ __launch_bounds__(256) void transpose_all(
    const float* __restrict__ W2, unsigned short* __restrict__ W2t,
    const float* __restrict__ Wv, unsigned short* __restrict__ Wvt,
    const float* __restrict__ W1, unsigned short* __restrict__ W1t,
    const float* __restrict__ Wk, const float* __restrict__ Wq,
    unsigned short* __restrict__ Wqkt)
{
    __shared__ float t[32][33];
    const int id = blockIdx.x;
    const float* in; unsigned short* out; int K, N, bx, by;
    if (id < 8000)      { in = W2; out = W2t;  K = 256; N = 32000; by = id & 7;  bx = id >> 3; }
    else if (id < 8384) { int q = id - 8000; in = Wv; out = Wvt;  K = 768; N = 512; bx = q & 15; by = q >> 4; }
    else if (id < 8512) { int q = id - 8384; in = W1; out = W1t;  K = 512; N = 256; bx = q & 7;  by = q >> 3; }
    else if (id < 8608) { int q = id - 8512; in = Wk; out = Wqkt; K = 768; N = 128; bx = q & 3;  by = q >> 2; }
    else                { int q = id - 8608; in = Wq; out = Wqkt + (size_t)128 * 768; K = 768; N = 128; bx = q & 3; by = q >> 2; }

    const int tx = threadIdx.x & 31, ty = threadIdx.x >> 5;
    #pragma unroll
    for (int i = 0; i < 4; ++i) {
        int k = by * 32 + ty + i * 8, n = bx * 32 + tx;
        t[ty + i * 8][tx] = in[(size_t)k * N + n];
    }
    __syncthreads();
    #pragma unroll
    for (int i = 0; i < 4; ++i) {
        int n = bx * 32 + ty + i * 8, k = by * 32 + tx;
        out[(size_t)n * K + k] = f2bf(t[tx][ty + i * 8]);
    }
}

// ---------------- proj_qk: one pass over x -> Kall = relu(x@Wk+bk), Pq = x@Wq ----------------
// Tile 64x256, 256 threads (4 waves, each 64x64), 2-phase dbuf, swizzled LDS (conflict-free).
__global__ __launch_bounds__(256) void proj_qk(
    const float* __restrict__ x, const unsigned short* __restrict__ Bt,
    const float* __restrict__ bk,
    unsigned short* __restrict__ Kall,   // [49152][128] bf16
    unsigned short* __restrict__ Pq)     // [49152][128] bf16
{
    __shared__ __align__(16) unsigned short As[2][64 * 32];    // 2 x 4 KB, XOR-swizzled slots
    __shared__ __align__(16) unsigned short Bs[2][256 * 32];   // 2 x 16 KB, source-swizzled
    const int tid = threadIdx.x;
    const int wid = tid >> 6, lane = tid & 63;
    const int wn = wid * 64;
    const int lr = lane & 15, g = lane >> 4;
    const int r0 = blockIdx.x * 64;
    const int K = 768, NT = K / 32;

    const int arow = tid >> 2;                       // 0..63
    const int aslot = (tid & 3) ^ (arow & 3);        // swizzled dest slot (16B units)
    const int bslot = (lane & 3) ^ ((lane >> 2) & 3);  // src k-slot for B staging

    f32x4 acc[4][4] = {};

    // prologue: tile 0
    float4 a0 = *(const float4*)(x + (size_t)(r0 + arow) * K + (tid & 3) * 8);
    float4 a1 = *(const float4*)(x + (size_t)(r0 + arow) * K + (tid & 3) * 8 + 4);
    {
        unsigned short v[8];
        v[0] = f2bf(a0.x); v[1] = f2bf(a0.y); v[2] = f2bf(a0.z); v[3] = f2bf(a0.w);
        v[4] = f2bf(a1.x); v[5] = f2bf(a1.y); v[6] = f2bf(a1.z); v[7] = f2bf(a1.w);
        *(uint4*)&As[0][arow * 32 + aslot * 8] = *(uint4*)v;
    }
    #pragma unroll
    for (int c = 0; c < 4; ++c) {
        int rr = wid * 64 + c * 16;
        gld_lds16(Bt + (size_t)(rr + (lane >> 2)) * K + bslot * 8, &Bs[0][rr * 32]);
    }
    __syncthreads();

    for (int t = 0; t < NT; ++t) {
        const int cur = t & 1, nxt = cur ^ 1;
        if (t + 1 < NT) {
            const int k0 = (t + 1) * 32;
            a0 = *(const float4*)(x + (size_t)(r0 + arow) * K + k0 + (tid & 3) * 8);
            a1 = *(const float4*)(x + (size_t)(r0 + arow) * K + k0 + (tid & 3) * 8 + 4);
            #pragma unroll
            for (int c = 0; c < 4; ++c) {
                int rr = wid * 64 + c * 16;
                gld_lds16(Bt + (size_t)(rr + (lane >> 2)) * K + k0 + bslot * 8, &Bs[nxt][rr * 32]);
            }
        }

        bf16x8 aF[4], bF[4];
        const int rslot = (g ^ (lr & 3)) * 8;
        #pragma unroll
        for (int mm = 0; mm < 4; ++mm) aF[mm] = *(const bf16x8*)&As[cur][(mm * 16 + lr) * 32 + rslot];
        #pragma unroll
        for (int nn = 0; nn < 4; ++nn) bF[nn] = *(const bf16x8*)&Bs[cur][(wn + nn * 16 + lr) * 32 + rslot];
        #pragma unroll
        for (int mm = 0; mm < 4; ++mm)
            #pragma unroll
            for (int nn = 0; nn < 4; ++nn)
                acc[mm][nn] = __builtin_amdgcn_mfma_f32_16x16x32_bf16(bF[nn], aF[mm], acc[mm][nn], 0, 0, 0);

        if (t + 1 < NT) {
            unsigned short v[8];
            v[0] = f2bf(a0.x); v[1] = f2bf(a0.y); v[2] = f2bf(a0.z); v[3] = f2bf(a0.w);
            v[4] = f2bf(a1.x); v[5] = f2bf(a1.y); v[6] = f2bf(a1.z); v[7] = f2bf(a1.w);
            *(uint4*)&As[nxt][arow * 32 + aslot * 8] = *(uint4*)v;
        }
        __syncthreads();
    }

    // swapped epilogue: row = lr-side, 4 consecutive cols per lane
    #pragma unroll
    for (int mm = 0; mm < 4; ++mm)
        #pragma unroll
        for (int nn = 0; nn < 4; ++nn) {
            const int row = r0 + mm * 16 + lr;
            const int colb = wn + nn * 16 + g * 4;
            unsigned short o[4];
            if (colb < 128) {
                #pragma unroll
                for (int reg = 0; reg < 4; ++reg) {
                    float kv = acc[mm][nn][reg] + bk[colb + reg];
                    o[reg] = f2bf(kv > 0.f ? kv : 0.f);
                }
                *(ushort4*)&Kall[(size_t)row * 128 + colb] = *(ushort4*)o;
            } else {
                #pragma unroll
                for (int reg = 0; reg < 4; ++reg) o[reg] = f2bf(acc[mm][nn][reg]);
                *(ushort4*)&Pq[(size_t)row * 128 + (colb - 128)] = *(ushort4*)o;
            }
        }
}

// ---------------- scores + softmax + weighted hidden sum (q fused in) ----------------
__global__ __launch_bounds__(256) void scores_hbar(
    const float* __restrict__ x,             // [12][2][2048][768] fp32
    const unsigned short* __restrict__ Pq,   // [49152][128] bf16
    const float* __restrict__ bq,            // [128]
    const unsigned short* __restrict__ Kall, // [49152][128] bf16
    unsigned short* __restrict__ hbar)       // [4096][768] bf16
{
    const int wid = threadIdx.x >> 6, lane = threadIdx.x & 63;
    const int r = blockIdx.x * 4 + wid;
    const int b = r >> 11, s = r & 2047;

    float qa = 0.f, qb_ = 0.f;
    #pragma unroll
    for (int l = 0; l < 12; ++l) {
        const unsigned short* prow = Pq + ((size_t)(l * 2 + b) * Snum + s) * 128 + lane * 2;
        unsigned int u = *(const unsigned int*)prow;
        qa += bf2f((unsigned short)(u & 0xFFFF));
        qb_ += bf2f((unsigned short)(u >> 16));
    }
    float q0 = qa * (1.0f / 12.0f) + bq[lane * 2];
    float q1 = qb_ * (1.0f / 12.0f) + bq[lane * 2 + 1];
    q0 = q0 > 0.f ? q0 : 0.f;
    q1 = q1 > 0.f ? q1 : 0.f;
    q0 = bf2f(f2bf(q0)); q1 = bf2f(f2bf(q1));

    float sc[12];
    #pragma unroll
    for (int l = 0; l < 12; ++l) {
        const unsigned short* krow = Kall + ((size_t)(l * 2 + b) * Snum + s) * 128 + lane * 2;
        unsigned int u = *(const unsigned int*)krow;
        float p = q0 * bf2f((unsigned short)(u & 0xFFFF)) + q1 * bf2f((unsigned short)(u >> 16));
        #pragma unroll
        for (int off = 32; off > 0; off >>= 1) p += __shfl_xor(p, off, 64);
        sc[l] = p * SCALE;
    }
    float m = sc[0];
    #pragma unroll
    for (int l = 1; l < 12; ++l) m = fmaxf(m, sc[l]);
    float att[12], den = 0.f;
    #pragma unroll
    for (int l = 0; l < 12; ++l) { att[l] = __expf(sc[l] - m); den += att[l]; }
    const float inv = 1.0f / den;
    #pragma unroll
    for (int l = 0; l < 12; ++l) att[l] *= inv;

    #pragma unroll
    for (int jv = 0; jv < 3; ++jv) {
        const int d0 = jv * 256 + lane * 4;
        float a0 = 0.f, a1 = 0.f, a2 = 0.f, a3 = 0.f;
        #pragma unroll
        for (int l = 0; l < 12; ++l) {
            const float4 v = *(const float4*)(x + ((size_t)(l * 2 + b) * Snum + s) * 768 + d0);
            a0 += att[l] * v.x; a1 += att[l] * v.y; a2 += att[l] * v.z; a3 += att[l] * v.w;
        }
        ushort4 o;
        o.x = f2bf(a0); o.y = f2bf(a1); o.z = f2bf(a2); o.w = f2bf(a3);
        *(ushort4*)(hbar + (size_t)r * 768 + d0) = o;
    }
}

// ---------------- 64x64 bf16 MFMA GEMM, swapped epilogue (ushort4/float4 stores) ----------------
template <int RELU, int OUT_BF16>
__global__ __launch_bounds__(256) void gemm64(
    const unsigned short* __restrict__ A, const unsigned short* __restrict__ Bt,
    const float* __restrict__ bias, void* __restrict__ out, int M, int N, int K)
{
    __shared__ __align__(16) unsigned short As[64][40];
    __shared__ __align__(16) unsigned short Bs[64][40];
    const int tid = threadIdx.x;
    const int bn = blockIdx.x, bm = blockIdx.y;
    const int wid = tid >> 6, lane = tid & 63;
    const int wm = (wid >> 1) * 32, wn = (wid & 1) * 32;
    const int lr = lane & 15, g = lane >> 4;
    const int r0 = bm * 64, c0 = bn * 64;

    f32x4 acc[2][2] = {};
    const int row = tid >> 2, kc = (tid & 3) * 8;

    for (int k0 = 0; k0 < K; k0 += 32) {
        __syncthreads();
        *(uint4*)&As[row][kc] = *(const uint4*)(A  + (size_t)(r0 + row) * K + k0 + kc);
        *(uint4*)&Bs[row][kc] = *(const uint4*)(Bt + (size_t)(c0 + row) * K + k0 + kc);
        __syncthreads();

        bf16x8 aF[2], bF[2];
        #pragma unroll
        for (int mm = 0; mm < 2; ++mm) aF[mm] = *(const bf16x8*)&As[wm + mm * 16 + lr][g * 8];
        #pragma unroll
        for (int nn = 0; nn < 2; ++nn) bF[nn] = *(const bf16x8*)&Bs[wn + nn * 16 + lr][g * 8];
        #pragma unroll
        for (int mm = 0; mm < 2; ++mm)
            #pragma unroll
            for (int nn = 0; nn < 2; ++nn)
                acc[mm][nn] = __builtin_amdgcn_mfma_f32_16x16x32_bf16(bF[nn], aF[mm], acc[mm][nn], 0, 0, 0);
    }

    #pragma unroll
    for (int mm = 0; mm < 2; ++mm)
        #pragma unroll
        for (int nn = 0; nn < 2; ++nn) {
            const int orow = r0 + wm + mm * 16 + lr;
            const int colb = c0 + wn + nn * 16 + g * 4;
            float vr[4];
            #pragma unroll
            for (int reg = 0; reg < 4; ++reg) {
                float v = acc[mm][nn][reg] + bias[colb + reg];
                vr[reg] = (RELU && v < 0.f) ? 0.f : v;
            }
            if (OUT_BF16) {
                unsigned short o[4];
                #pragma unroll
                for (int reg = 0; reg < 4; ++reg) o[reg] = f2bf(vr[reg]);
                *(ushort4*)&((unsigned short*)out)[(size_t)orow * N + colb] = *(ushort4*)o;
            } else {
                *(float4*)&((float*)out)[(size_t)orow * N + colb] = *(float4*)vr;
            }
        }
}

// ---------------- final GEMM: out = mid @ W2t^T + b2, fp32, BK=64 dbuf, swizzled, swapped ----------------
// M=4096, N=32000, K=256. Grid 8000, XCD-swizzled.
__global__ __launch_bounds__(256) void gemm_out(
    const unsigned short* __restrict__ A,   // [4096][256] bf16
    const unsigned short* __restrict__ Bt,  // [32000][256] bf16
    const float* __restrict__ bias, float* __restrict__ out)
{
    __shared__ __align__(16) unsigned short As[2][128 * 64];  // 2 x 16 KB
    __shared__ __align__(16) unsigned short Bs[2][128 * 64];
    const int K = 256, N = 32000, NT = 4;
    const int orig = blockIdx.x;
    const int swz = (orig & 7) * 1000 + (orig >> 3);
    const int bn = swz >> 5, bm = swz & 31;
    const int tid = threadIdx.x;
    const int wid = tid >> 6, lane = tid & 63;
    const int wm = (wid >> 1) * 64, wn = (wid & 1) * 64;
    const int lr = lane & 15, g = lane >> 4;
    const int r0 = bm * 128, c0 = bn * 128;

    const int srow = lane >> 3;                  // 0..7 (row within 8-row stage group)
    const int kslot = (lane & 7) ^ (srow & 7);   // inverse-swizzled source k-slot

    f32x4 acc[4][4] = {};

    // prologue: stage K-tile 0 (A rows / B cols: wave wid covers 32, 4 groups of 8)
    #pragma unroll
    for (int c = 0; c < 4; ++c) {
        const int rb = wid * 32 + c * 8;
        gld_lds16(A  + (size_t)(r0 + rb + srow) * K + kslot * 8, &As[0][rb * 64]);
        gld_lds16(Bt + (size_t)(c0 + rb + srow) * K + kslot * 8, &Bs[0][rb * 64]);
    }
    __syncthreads();

    for (int t = 0; t < NT; ++t) {
        const int cur = t & 1, nxt = cur ^ 1;
        if (t + 1 < NT) {
            const int k0 = (t + 1) * 64;
            #pragma unroll
            for (int c = 0; c < 4; ++c) {
                const int rb = wid * 32 + c * 8;
                gld_lds16(A  + (size_t)(r0 + rb + srow) * K + k0 + kslot * 8, &As[nxt][rb * 64]);
                gld_lds16(Bt + (size_t)(c0 + rb + srow) * K + k0 + kslot * 8, &Bs[nxt][rb * 64]);
            }
        }

        #pragma unroll
        for (int kk = 0; kk < 2; ++kk) {
            bf16x8 aF[4], bF[4];
            #pragma unroll
            for (int mm = 0; mm < 4; ++mm)
                aF[mm] = *(const bf16x8*)&As[cur][(wm + mm * 16 + lr) * 64 + (((kk * 4 + g) ^ (lr & 7)) * 8)];
            #pragma unroll
            for (int nn = 0; nn < 4; ++nn)
                bF[nn] = *(const bf16x8*)&Bs[cur][(wn + nn * 16 + lr) * 64 + (((kk * 4 + g) ^ (lr & 7)) * 8)];
            #pragma unroll
            for (int mm = 0; mm < 4; ++mm)
                #pragma unroll
                for (int nn = 0; nn < 4; ++nn)
                    acc[mm][nn] = __builtin_amdgcn_mfma_f32_16x16x32_bf16(bF[nn], aF[mm], acc[mm][nn], 0, 0, 0);
        }
        __syncthreads();
    }

    // swapped epilogue: float4 stores (lane owns 4 consecutive cols)
    #pragma unroll
    for (int mm = 0; mm < 4; ++mm)
        #pragma unroll
        for (int nn = 0; nn < 4; ++nn) {
            const int row = r0 + wm + mm * 16 + lr;
            const int colb = c0 + wn + nn * 16 + g * 4;
            const float4 b4 = *(const float4*)&bias[colb];
            float o[4];
            o[0] = acc[mm][nn][0] + b4.x;
            o[1] = acc[mm][nn][1] + b4.y;
            o[2] = acc[mm][nn][2] + b4.z;
            o[3] = acc[mm][nn][3] + b4.w;
            *(float4*)&out[(size_t)row * N + colb] = *(float4*)o;
        }
}

extern "C" void kernel_launch(void* const* d_in, const int* in_sizes, int n_in,
                              void* d_out, int out_size, void* d_ws, size_t ws_size,
                              hipStream_t stream) {
    (void)in_sizes; (void)n_in; (void)out_size; (void)ws_size;

    const float* x  = (const float*)d_in[0];
    const float* Wq = (const float*)d_in[1];
    const float* bq = (const float*)d_in[2];
    const float* Wk = (const float*)d_in[3];
    const float* bk = (const float*)d_in[4];
    const float* Wv = (const float*)d_in[5];
    const float* bv = (const float*)d_in[6];
    const float* W1 = (const float*)d_in[7];
    const float* b1 = (const float*)d_in[8];
    const float* W2 = (const float*)d_in[9];
    const float* b2 = (const float*)d_in[10];

    char* p = (char*)d_ws;
    unsigned short* Wqkt  = (unsigned short*)p; p += (size_t)256 * 768 * 2;   // [Wk^T | Wq^T]
    unsigned short* Wvt   = (unsigned short*)p; p += (size_t)512 * 768 * 2;
    unsigned short* W1t   = (unsigned short*)p; p += (size_t)256 * 512 * 2;
    unsigned short* W2t   = (unsigned short*)p; p += (size_t)32000 * 256 * 2;
    unsigned short* Kall  = (unsigned short*)p; p += (size_t)49152 * 128 * 2;
    unsigned short* Pq    = (unsigned short*)p; p += (size_t)49152 * 128 * 2;
    unsigned short* hbar  = (unsigned short*)p; p += (size_t)4096 * 768 * 2;
    unsigned short* aggb  = (unsigned short*)p; p += (size_t)4096 * 512 * 2;
    unsigned short* midb  = (unsigned short*)p; p += (size_t)4096 * 256 * 2;

    // all weight transposes in one launch
    transpose_all<<<dim3(8704), dim3(256), 0, stream>>>(
        W2, W2t, Wv, Wvt, W1, W1t, Wk, Wq, Wqkt);

    // one pass over x: Kall = relu(x@Wk+bk), Pq = x@Wq
    proj_qk<<<dim3(49152 / 64), dim3(256), 0, stream>>>(x, Wqkt, bk, Kall, Pq);

    // scores (q fused) -> softmax -> hbar
    scores_hbar<<<dim3(1024), dim3(256), 0, stream>>>(x, Pq, bq, Kall, hbar);

    // agg = hbar @ Wv + bv
    gemm64<0, 1><<<dim3(512 / 64, 4096 / 64), dim3(256), 0, stream>>>(
        hbar, Wvt, bv, aggb, 4096, 512, 768);

    // mid = relu(agg @ W1 + b1)
    gemm64<1, 1><<<dim3(256 / 64, 4096 / 64), dim3(256), 0, stream>>>(
        aggb, W1t, b1, midb, 4096, 256, 512);

    // out = mid @ W2 + b2  (fp32)
    gemm_out<<<dim3(8000), dim3(256), 0, stream>>>(midb, W2t, b2, (float*)d_out);
}

// Round 6
// 281.748 us; speedup vs baseline: 1.3426x; 1.3426x over previous
//
#include <hip/hip_runtime.h>

#define Snum 2048
#define SCALE 0.08838834764831845f

typedef __attribute__((ext_vector_type(8))) __bf16 bf16x8;
typedef __attribute__((ext_vector_type(4))) float f32x4;

__device__ inline unsigned short f2bf(float f) {
    unsigned int u = __float_as_uint(f);
    unsigned int r = u + 0x7FFFu + ((u >> 16) & 1u);
    return (unsigned short)(r >> 16);
}
__device__ inline float bf2f(unsigned short u) {
    return __uint_as_float(((unsigned)u) << 16);
}
__device__ inline void gld_lds16(const unsigned short* g, unsigned short* l) {
    __builtin_amdgcn_global_load_lds(
        (const __attribute__((address_space(1))) unsigned int*)g,
        (__attribute__((address_space(3))) unsigned int*)l, 16, 0, 0);
}

// ---------------- small weight transposes (Wv, W1, Wk, Wq): [K][N] fp32 -> [N][K] bf16 ----------------
__global__ __launch_bounds__(256) void transpose_small(
    const float* __restrict__ Wv, unsigned short* __restrict__ Wvt,
    const float* __restrict__ W1, unsigned short* __restrict__ W1t,
    const float* __restrict__ Wk, const float* __restrict__ Wq,
    unsigned short* __restrict__ Wqkt)
{
    __shared__ float t[32][33];
    const int id = blockIdx.x;
    const float* in; unsigned short* out; int K, N, bx, by;
    if (id < 384)      { int q = id;       in = Wv; out = Wvt;  K = 768; N = 512; bx = q & 15; by = q >> 4; }
    else if (id < 512) { int q = id - 384; in = W1; out = W1t;  K = 512; N = 256; bx = q & 7;  by = q >> 3; }
    else if (id < 608) { int q = id - 512; in = Wk; out = Wqkt; K = 768; N = 128; bx = q & 3;  by = q >> 2; }
    else               { int q = id - 608; in = Wq; out = Wqkt + (size_t)128 * 768; K = 768; N = 128; bx = q & 3; by = q >> 2; }

    const int tx = threadIdx.x & 31, ty = threadIdx.x >> 5;
    #pragma unroll
    for (int i = 0; i < 4; ++i) {
        int k = by * 32 + ty + i * 8, n = bx * 32 + tx;
        t[ty + i * 8][tx] = in[(size_t)k * N + n];
    }
    __syncthreads();
    #pragma unroll
    for (int i = 0; i < 4; ++i) {
        int n = bx * 32 + ty + i * 8, k = by * 32 + tx;
        out[(size_t)n * K + k] = f2bf(t[tx][ty + i * 8]);
    }
}

// ---------------- proj_qk: one pass over x -> Kall = relu(x@Wk+bk), Pq = x@Wq ----------------
// Tile 128x256, 512 threads (8 waves as 2Mx4N of 64x64), 2-phase dbuf, linear LDS (m97-style).
__global__ __launch_bounds__(512) void proj_qk(
    const float* __restrict__ x, const unsigned short* __restrict__ Bt,
    const float* __restrict__ bk,
    unsigned short* __restrict__ Kall,   // [49152][128] bf16
    unsigned short* __restrict__ Pq)     // [49152][128] bf16
{
    __shared__ __align__(16) unsigned short As[2][128 * 32];   // 2 x 8 KB
    __shared__ __align__(16) unsigned short Bs[2][256 * 32];   // 2 x 16 KB
    const int tid = threadIdx.x;
    const int wid = tid >> 6, lane = tid & 63;
    const int wm = (wid >> 2) * 64, wn = (wid & 3) * 64;
    const int lr = lane & 15, g = lane >> 4;
    const int r0 = blockIdx.x * 128;
    const int K = 768, NT = 24;

    const int arow = tid >> 2, akc = (tid & 3) * 8;  // A: 128 rows x 32 k, 8 floats/thread

    f32x4 acc[4][4] = {};

    // prologue: tile 0
    float4 a0 = *(const float4*)(x + (size_t)(r0 + arow) * K + akc);
    float4 a1 = *(const float4*)(x + (size_t)(r0 + arow) * K + akc + 4);
    {
        unsigned short v[8];
        v[0] = f2bf(a0.x); v[1] = f2bf(a0.y); v[2] = f2bf(a0.z); v[3] = f2bf(a0.w);
        v[4] = f2bf(a1.x); v[5] = f2bf(a1.y); v[6] = f2bf(a1.z); v[7] = f2bf(a1.w);
        *(uint4*)&As[0][arow * 32 + akc] = *(uint4*)v;
    }
    #pragma unroll
    for (int c = 0; c < 2; ++c) {
        int rr = wid * 32 + c * 16;
        gld_lds16(Bt + (size_t)(rr + (lane >> 2)) * K + (lane & 3) * 8, &Bs[0][rr * 32]);
    }
    __syncthreads();

    for (int t = 0; t < NT; ++t) {
        const int cur = t & 1, nxt = cur ^ 1;
        if (t + 1 < NT) {
            const int k0 = (t + 1) * 32;
            a0 = *(const float4*)(x + (size_t)(r0 + arow) * K + k0 + akc);
            a1 = *(const float4*)(x + (size_t)(r0 + arow) * K + k0 + akc + 4);
            #pragma unroll
            for (int c = 0; c < 2; ++c) {
                int rr = wid * 32 + c * 16;
                gld_lds16(Bt + (size_t)(rr + (lane >> 2)) * K + k0 + (lane & 3) * 8,
                          &Bs[nxt][rr * 32]);
            }
        }

        bf16x8 aF[4], bF[4];
        #pragma unroll
        for (int mm = 0; mm < 4; ++mm) aF[mm] = *(const bf16x8*)&As[cur][(wm + mm * 16 + lr) * 32 + g * 8];
        #pragma unroll
        for (int nn = 0; nn < 4; ++nn) bF[nn] = *(const bf16x8*)&Bs[cur][(wn + nn * 16 + lr) * 32 + g * 8];
        #pragma unroll
        for (int mm = 0; mm < 4; ++mm)
            #pragma unroll
            for (int nn = 0; nn < 4; ++nn)
                acc[mm][nn] = __builtin_amdgcn_mfma_f32_16x16x32_bf16(bF[nn], aF[mm], acc[mm][nn], 0, 0, 0);

        if (t + 1 < NT) {
            unsigned short v[8];
            v[0] = f2bf(a0.x); v[1] = f2bf(a0.y); v[2] = f2bf(a0.z); v[3] = f2bf(a0.w);
            v[4] = f2bf(a1.x); v[5] = f2bf(a1.y); v[6] = f2bf(a1.z); v[7] = f2bf(a1.w);
            *(uint4*)&As[nxt][arow * 32 + akc] = *(uint4*)v;
        }
        __syncthreads();
    }

    // swapped epilogue: lane owns 4 consecutive cols
    #pragma unroll
    for (int mm = 0; mm < 4; ++mm)
        #pragma unroll
        for (int nn = 0; nn < 4; ++nn) {
            const int row = r0 + wm + mm * 16 + lr;
            const int colb = wn + nn * 16 + g * 4;
            unsigned short o[4];
            if (colb < 128) {
                #pragma unroll
                for (int reg = 0; reg < 4; ++reg) {
                    float kv = acc[mm][nn][reg] + bk[colb + reg];
                    o[reg] = f2bf(kv > 0.f ? kv : 0.f);
                }
                *(ushort4*)&Kall[(size_t)row * 128 + colb] = *(ushort4*)o;
            } else {
                #pragma unroll
                for (int reg = 0; reg < 4; ++reg) o[reg] = f2bf(acc[mm][nn][reg]);
                *(ushort4*)&Pq[(size_t)row * 128 + (colb - 128)] = *(ushort4*)o;
            }
        }
}

// ---------------- scores + softmax + hbar, with W2 transpose blocks riding along ----------------
__global__ __launch_bounds__(256) void scores_plus_w2t(
    const float* __restrict__ x,             // [12][2][2048][768] fp32
    const unsigned short* __restrict__ Pq,   // [49152][128] bf16
    const float* __restrict__ bq,            // [128]
    const unsigned short* __restrict__ Kall, // [49152][128] bf16
    unsigned short* __restrict__ hbar,       // [4096][768] bf16
    const float* __restrict__ W2, unsigned short* __restrict__ W2t)
{
    if (blockIdx.x >= 1024) {
        // W2 transpose role: [256][32000] fp32 -> [32000][256] bf16
        __shared__ float t[32][33];
        const int id = blockIdx.x - 1024;        // 0..7999
        const int bx = id >> 3, by = id & 7;     // bx: N/32, by: K/32
        const int tx = threadIdx.x & 31, ty = threadIdx.x >> 5;
        #pragma unroll
        for (int i = 0; i < 4; ++i) {
            int k = by * 32 + ty + i * 8, n = bx * 32 + tx;
            t[ty + i * 8][tx] = W2[(size_t)k * 32000 + n];
        }
        __syncthreads();
        #pragma unroll
        for (int i = 0; i < 4; ++i) {
            int n = bx * 32 + ty + i * 8, k = by * 32 + tx;
            W2t[(size_t)n * 256 + k] = f2bf(t[tx][ty + i * 8]);
        }
        return;
    }

    const int wid = threadIdx.x >> 6, lane = threadIdx.x & 63;
    const int r = blockIdx.x * 4 + wid;
    const int b = r >> 11, s = r & 2047;

    float qa = 0.f, qb_ = 0.f;
    #pragma unroll
    for (int l = 0; l < 12; ++l) {
        const unsigned short* prow = Pq + ((size_t)(l * 2 + b) * Snum + s) * 128 + lane * 2;
        unsigned int u = *(const unsigned int*)prow;
        qa += bf2f((unsigned short)(u & 0xFFFF));
        qb_ += bf2f((unsigned short)(u >> 16));
    }
    float q0 = qa * (1.0f / 12.0f) + bq[lane * 2];
    float q1 = qb_ * (1.0f / 12.0f) + bq[lane * 2 + 1];
    q0 = q0 > 0.f ? q0 : 0.f;
    q1 = q1 > 0.f ? q1 : 0.f;
    q0 = bf2f(f2bf(q0)); q1 = bf2f(f2bf(q1));

    float sc[12];
    #pragma unroll
    for (int l = 0; l < 12; ++l) {
        const unsigned short* krow = Kall + ((size_t)(l * 2 + b) * Snum + s) * 128 + lane * 2;
        unsigned int u = *(const unsigned int*)krow;
        float p = q0 * bf2f((unsigned short)(u & 0xFFFF)) + q1 * bf2f((unsigned short)(u >> 16));
        #pragma unroll
        for (int off = 32; off > 0; off >>= 1) p += __shfl_xor(p, off, 64);
        sc[l] = p * SCALE;
    }
    float m = sc[0];
    #pragma unroll
    for (int l = 1; l < 12; ++l) m = fmaxf(m, sc[l]);
    float att[12], den = 0.f;
    #pragma unroll
    for (int l = 0; l < 12; ++l) { att[l] = __expf(sc[l] - m); den += att[l]; }
    const float inv = 1.0f / den;
    #pragma unroll
    for (int l = 0; l < 12; ++l) att[l] *= inv;

    #pragma unroll
    for (int jv = 0; jv < 3; ++jv) {
        const int d0 = jv * 256 + lane * 4;
        float a0 = 0.f, a1 = 0.f, a2 = 0.f, a3 = 0.f;
        #pragma unroll
        for (int l = 0; l < 12; ++l) {
            const float4 v = *(const float4*)(x + ((size_t)(l * 2 + b) * Snum + s) * 768 + d0);
            a0 += att[l] * v.x; a1 += att[l] * v.y; a2 += att[l] * v.z; a3 += att[l] * v.w;
        }
        ushort4 o;
        o.x = f2bf(a0); o.y = f2bf(a1); o.z = f2bf(a2); o.w = f2bf(a3);
        *(ushort4*)(hbar + (size_t)r * 768 + d0) = o;
    }
}

// ---------------- 64x64 bf16 MFMA GEMM, swapped epilogue ----------------
template <int RELU, int OUT_BF16>
__global__ __launch_bounds__(256) void gemm64(
    const unsigned short* __restrict__ A, const unsigned short* __restrict__ Bt,
    const float* __restrict__ bias, void* __restrict__ out, int M, int N, int K)
{
    __shared__ __align__(16) unsigned short As[64][40];
    __shared__ __align__(16) unsigned short Bs[64][40];
    const int tid = threadIdx.x;
    const int bn = blockIdx.x, bm = blockIdx.y;
    const int wid = tid >> 6, lane = tid & 63;
    const int wm = (wid >> 1) * 32, wn = (wid & 1) * 32;
    const int lr = lane & 15, g = lane >> 4;
    const int r0 = bm * 64, c0 = bn * 64;

    f32x4 acc[2][2] = {};
    const int row = tid >> 2, kc = (tid & 3) * 8;

    for (int k0 = 0; k0 < K; k0 += 32) {
        __syncthreads();
        *(uint4*)&As[row][kc] = *(const uint4*)(A  + (size_t)(r0 + row) * K + k0 + kc);
        *(uint4*)&Bs[row][kc] = *(const uint4*)(Bt + (size_t)(c0 + row) * K + k0 + kc);
        __syncthreads();

        bf16x8 aF[2], bF[2];
        #pragma unroll
        for (int mm = 0; mm < 2; ++mm) aF[mm] = *(const bf16x8*)&As[wm + mm * 16 + lr][g * 8];
        #pragma unroll
        for (int nn = 0; nn < 2; ++nn) bF[nn] = *(const bf16x8*)&Bs[wn + nn * 16 + lr][g * 8];
        #pragma unroll
        for (int mm = 0; mm < 2; ++mm)
            #pragma unroll
            for (int nn = 0; nn < 2; ++nn)
                acc[mm][nn] = __builtin_amdgcn_mfma_f32_16x16x32_bf16(bF[nn], aF[mm], acc[mm][nn], 0, 0, 0);
    }

    #pragma unroll
    for (int mm = 0; mm < 2; ++mm)
        #pragma unroll
        for (int nn = 0; nn < 2; ++nn) {
            const int orow = r0 + wm + mm * 16 + lr;
            const int colb = c0 + wn + nn * 16 + g * 4;
            float vr[4];
            #pragma unroll
            for (int reg = 0; reg < 4; ++reg) {
                float v = acc[mm][nn][reg] + bias[colb + reg];
                vr[reg] = (RELU && v < 0.f) ? 0.f : v;
            }
            if (OUT_BF16) {
                unsigned short o[4];
                #pragma unroll
                for (int reg = 0; reg < 4; ++reg) o[reg] = f2bf(vr[reg]);
                *(ushort4*)&((unsigned short*)out)[(size_t)orow * N + colb] = *(ushort4*)o;
            } else {
                *(float4*)&((float*)out)[(size_t)orow * N + colb] = *(float4*)vr;
            }
        }
}

// ---------------- final GEMM: out = mid @ W2t^T + b2, fp32, BK=32/32KB dbuf, nt stores ----------------
// M=4096, N=32000, K=256. Grid 8000, XCD-swizzled.
__global__ __launch_bounds__(256) void gemm_out(
    const unsigned short* __restrict__ A,   // [4096][256] bf16
    const unsigned short* __restrict__ Bt,  // [32000][256] bf16
    const float* __restrict__ bias, float* __restrict__ out)
{
    __shared__ __align__(16) unsigned short As[2][128 * 32];  // 2 x 8 KB
    __shared__ __align__(16) unsigned short Bs[2][128 * 32];
    const int K = 256, N = 32000, NT = 8;
    const int orig = blockIdx.x;
    const int swz = (orig & 7) * 1000 + (orig >> 3);
    const int bn = swz >> 5, bm = swz & 31;
    const int tid = threadIdx.x;
    const int wid = tid >> 6, lane = tid & 63;
    const int wm = (wid >> 1) * 64, wn = (wid & 1) * 64;
    const int lr = lane & 15, g = lane >> 4;
    const int r0 = bm * 128, c0 = bn * 128;

    f32x4 acc[4][4] = {};

    // prologue: stage K-tile 0
    #pragma unroll
    for (int c = 0; c < 2; ++c) {
        int rr = wid * 32 + c * 16;
        gld_lds16(A  + (size_t)(r0 + rr + (lane >> 2)) * K + (lane & 3) * 8, &As[0][rr * 32]);
        gld_lds16(Bt + (size_t)(c0 + rr + (lane >> 2)) * K + (lane & 3) * 8, &Bs[0][rr * 32]);
    }
    __syncthreads();

    for (int t = 0; t < NT; ++t) {
        const int cur = t & 1, nxt = cur ^ 1;
        if (t + 1 < NT) {
            const int k0 = (t + 1) * 32;
            #pragma unroll
            for (int c = 0; c < 2; ++c) {
                int rr = wid * 32 + c * 16;
                gld_lds16(A  + (size_t)(r0 + rr + (lane >> 2)) * K + k0 + (lane & 3) * 8, &As[nxt][rr * 32]);
                gld_lds16(Bt + (size_t)(c0 + rr + (lane >> 2)) * K + k0 + (lane & 3) * 8, &Bs[nxt][rr * 32]);
            }
        }

        bf16x8 aF[4], bF[4];
        #pragma unroll
        for (int mm = 0; mm < 4; ++mm) aF[mm] = *(const bf16x8*)&As[cur][(wm + mm * 16 + lr) * 32 + g * 8];
        #pragma unroll
        for (int nn = 0; nn < 4; ++nn) bF[nn] = *(const bf16x8*)&Bs[cur][(wn + nn * 16 + lr) * 32 + g * 8];
        #pragma unroll
        for (int mm = 0; mm < 4; ++mm)
            #pragma unroll
            for (int nn = 0; nn < 4; ++nn)
                acc[mm][nn] = __builtin_amdgcn_mfma_f32_16x16x32_bf16(bF[nn], aF[mm], acc[mm][nn], 0, 0, 0);
        __syncthreads();
    }

    // swapped epilogue: float4 nontemporal stores (lane owns 4 consecutive cols)
    #pragma unroll
    for (int mm = 0; mm < 4; ++mm)
        #pragma unroll
        for (int nn = 0; nn < 4; ++nn) {
            const int row = r0 + wm + mm * 16 + lr;
            const int colb = c0 + wn + nn * 16 + g * 4;
            const float4 b4 = *(const float4*)&bias[colb];
            f32x4 o = acc[mm][nn];
            o[0] += b4.x; o[1] += b4.y; o[2] += b4.z; o[3] += b4.w;
            __builtin_nontemporal_store(o, (f32x4*)&out[(size_t)row * N + colb]);
        }
}

extern "C" void kernel_launch(void* const* d_in, const int* in_sizes, int n_in,
                              void* d_out, int out_size, void* d_ws, size_t ws_size,
                              hipStream_t stream) {
    (void)in_sizes; (void)n_in; (void)out_size; (void)ws_size;

    const float* x  = (const float*)d_in[0];
    const float* Wq = (const float*)d_in[1];
    const float* bq = (const float*)d_in[2];
    const float* Wk = (const float*)d_in[3];
    const float* bk = (const float*)d_in[4];
    const float* Wv = (const float*)d_in[5];
    const float* bv = (const float*)d_in[6];
    const float* W1 = (const float*)d_in[7];
    const float* b1 = (const float*)d_in[8];
    const float* W2 = (const float*)d_in[9];
    const float* b2 = (const float*)d_in[10];

    char* p = (char*)d_ws;
    unsigned short* Wqkt  = (unsigned short*)p; p += (size_t)256 * 768 * 2;   // [Wk^T | Wq^T]
    unsigned short* Wvt   = (unsigned short*)p; p += (size_t)512 * 768 * 2;
    unsigned short* W1t   = (unsigned short*)p; p += (size_t)256 * 512 * 2;
    unsigned short* W2t   = (unsigned short*)p; p += (size_t)32000 * 256 * 2;
    unsigned short* Kall  = (unsigned short*)p; p += (size_t)49152 * 128 * 2;
    unsigned short* Pq    = (unsigned short*)p; p += (size_t)49152 * 128 * 2;
    unsigned short* hbar  = (unsigned short*)p; p += (size_t)4096 * 768 * 2;
    unsigned short* aggb  = (unsigned short*)p; p += (size_t)4096 * 512 * 2;
    unsigned short* midb  = (unsigned short*)p; p += (size_t)4096 * 256 * 2;

    // small weight transposes (Wqkt needed by proj_qk; Wvt/W1t by gemm64s)
    transpose_small<<<dim3(704), dim3(256), 0, stream>>>(Wv, Wvt, W1, W1t, Wk, Wq, Wqkt);

    // one pass over x: Kall = relu(x@Wk+bk), Pq = x@Wq
    proj_qk<<<dim3(49152 / 128), dim3(512), 0, stream>>>(x, Wqkt, bk, Kall, Pq);

    // scores (q fused) -> softmax -> hbar; W2 transpose rides along
    scores_plus_w2t<<<dim3(1024 + 8000), dim3(256), 0, stream>>>(
        x, Pq, bq, Kall, hbar, W2, W2t);

    // agg = hbar @ Wv + bv
    gemm64<0, 1><<<dim3(512 / 64, 4096 / 64), dim3(256), 0, stream>>>(
        hbar, Wvt, bv, aggb, 4096, 512, 768);

    // mid = relu(agg @ W1 + b1)
    gemm64<1, 1><<<dim3(256 / 64, 4096 / 64), dim3(256), 0, stream>>>(
        aggb, W1t, b1, midb, 4096, 256, 512);

    // out = mid @ W2 + b2  (fp32)
    gemm_out<<<dim3(8000), dim3(256), 0, stream>>>(midb, W2t, b2, (float*)d_out);
}